// Round 2
// baseline (253.134 us; speedup 1.0000x reference)
//
#include <hip/hip_runtime.h>
#include <hip/hip_bf16.h>

// B=128, S=256, E=768, C=4; M = B*S = 32768.
// 5 launches:
//  prep_q: qW1 partials fp32 [8][128][768] (single-barrier LDS GEMM, 96 blocks)
//  prep_rest: W1t8=fp8(W1[768:].T) | W2t8=fp8(W2.T) | segF8=fp8(segments)
//  K2:    H1f8[32768,768]fp8 = gelu(segF8 @ W1t8^T + b1 + sum qW1p[bag])   (fp8-MX MFMA)
//  K3:    partial preds pp[3][32768][4] = (gelu(H1f8 @ W2t8^T + b2) tile) @ W3-chunk
//  head:  out[128,4] = aggregate(softmax(pp0+pp1+pp2 + b3)) with shfl-based scans
// K2/K3 use 2-phase double-buffered LDS: prefetch next K-tile via global_load_lds
// BEFORE compute, single __syncthreads per K-step (T3 minimum recipe), plus
// bijective XCD-chunked block swizzle (T1).

typedef __attribute__((ext_vector_type(8))) short short8;
typedef __attribute__((ext_vector_type(8))) unsigned short ushort8;
typedef __attribute__((ext_vector_type(16))) float f32x16;
typedef __attribute__((ext_vector_type(8))) int i32x8;
typedef __attribute__((ext_vector_type(4))) int i32x4;

__device__ __forceinline__ unsigned short f2bf(float f) {
    union { float f; unsigned int u; } c; c.f = f;
    unsigned int u = c.u;
    unsigned int r = (u + 0x7FFFu + ((u >> 16) & 1u)) >> 16;  // RNE
    return (unsigned short)r;
}
__device__ __forceinline__ float bf2f(unsigned short u) {
    union { unsigned int u; float f; } c; c.u = ((unsigned int)u) << 16;
    return c.f;
}
__device__ __forceinline__ float gelu_fast(float x) {
    float x2 = x * x;
    float y2 = 1.5957691216057308f * (x + 0.044715f * x2 * x);
    float e = __expf(y2);
    float t = 1.0f - 2.0f * __builtin_amdgcn_rcpf(e + 1.0f);
    return 0.5f * x * (1.0f + t);
}

typedef const __attribute__((address_space(1))) void* gas_t;
typedef __attribute__((address_space(3))) void* las_t;
__device__ __forceinline__ void g2l16(const void* g, void* l) {
    __builtin_amdgcn_global_load_lds((gas_t)g, (las_t)l, 16, 0, 0);
}

// pack 4 floats -> 4 fp8 e4m3 bytes (RNE, saturating)
__device__ __forceinline__ unsigned int f4_to_fp8x4(float a, float b, float c, float d) {
    int lo = __builtin_amdgcn_cvt_pk_fp8_f32(a, b, 0, 0);
    return (unsigned int)__builtin_amdgcn_cvt_pk_fp8_f32(c, d, lo, 1);
}
__device__ __forceinline__ unsigned char f_to_fp8(float a) {
    return (unsigned char)(__builtin_amdgcn_cvt_pk_fp8_f32(a, a, 0, 0) & 0xFF);
}

// ---------------- prep_q: qW1 partials ----------------
// questions[128,768] @ W1[0:768,:768] -> qW1p[8 ksplits][128][768] fp32.
// grid 96 = 12 n-tiles x 8 k-splits; one barrier per block.
__global__ __launch_bounds__(256) void prep_q_kernel(
    const float* __restrict__ questions, const float* __restrict__ W1,
    float* __restrict__ qW1p)
{
    __shared__ __align__(16) float As[96][132];   // [k][m], padded stride
    __shared__ __align__(16) float Bs[96][64];    // [k][n]
    const int tid = threadIdx.x;
    const int nt = blockIdx.x % 12, sp = blockIdx.x / 12;
    const int n0 = nt * 64, kbeg = sp * 96;

    // stage A: questions[0:128, kbeg:kbeg+96] transposed to As[k][m]
    for (int i = tid; i < 3072; i += 256) {
        int row = i / 24, c4 = i % 24;
        float4 v = ((const float4*)questions)[row * 192 + (kbeg >> 2) + c4];
        int kb = c4 * 4;
        As[kb + 0][row] = v.x; As[kb + 1][row] = v.y;
        As[kb + 2][row] = v.z; As[kb + 3][row] = v.w;
    }
    // stage B: W1[kbeg:kbeg+96, n0:n0+64]
    for (int i = tid; i < 1536; i += 256) {
        int row = i / 16, c4 = i % 16;
        float4 v = ((const float4*)W1)[(size_t)(kbeg + row) * 192 + (n0 >> 2) + c4];
        *(float4*)&Bs[row][c4 * 4] = v;
    }
    __syncthreads();

    const int tm = tid >> 4, tn = tid & 15;   // 8 rows x 4 cols per thread
    float acc[8][4] = {};
    #pragma unroll 2
    for (int k = 0; k < 96; k++) {
        float4 a0 = *(const float4*)&As[k][tm * 8];
        float4 a1 = *(const float4*)&As[k][tm * 8 + 4];
        float4 b  = *(const float4*)&Bs[k][tn * 4];
        float ar[8] = {a0.x, a0.y, a0.z, a0.w, a1.x, a1.y, a1.z, a1.w};
        float br[4] = {b.x, b.y, b.z, b.w};
        #pragma unroll
        for (int i = 0; i < 8; i++)
            #pragma unroll
            for (int j = 0; j < 4; j++)
                acc[i][j] += ar[i] * br[j];
    }
    float* outp = qW1p + (size_t)sp * 128 * 768;
    #pragma unroll
    for (int i = 0; i < 8; i++) {
        int row = tm * 8 + i;
        *(float4*)&outp[(size_t)row * 768 + n0 + tn * 4] =
            make_float4(acc[i][0], acc[i][1], acc[i][2], acc[i][3]);
    }
}

// ---------------- prep_rest: transposes + segment conversion ----------------
#define PR_TR1E 144
#define PR_TR2E 216
#define PR_END  12504

__global__ __launch_bounds__(256) void prep_rest_kernel(
    const float* __restrict__ segments, unsigned char* __restrict__ segF8,
    const float* __restrict__ W1, unsigned char* __restrict__ W1t8,
    const float* __restrict__ W2, unsigned char* __restrict__ W2t8)
{
    __shared__ __align__(16) char sh[16640];
    const int bid = blockIdx.x, tid = threadIdx.x;

    if (bid < PR_TR2E) {
        // transpose 64x64 tile -> fp8 bytes
        const float* in; unsigned char* outp; int R, C, bx, by;
        if (bid < PR_TR1E) {
            int idx = bid; bx = idx % 12; by = idx / 12;
            in = W1 + 768 * 768; outp = W1t8; R = 768; C = 768;
        } else {
            int idx = bid - PR_TR1E; bx = idx % 6; by = idx / 6;
            in = W2; outp = W2t8; R = 768; C = 384;
        }
        float (*t)[65] = (float(*)[65])sh;
        int r0 = by * 64, c0 = bx * 64;
        int tx = tid & 63, ty = tid >> 6;
        #pragma unroll
        for (int p = 0; p < 16; p++) {
            int row = ty * 16 + p;
            t[row][tx] = in[(size_t)(r0 + row) * C + c0 + tx];
        }
        __syncthreads();
        #pragma unroll
        for (int p = 0; p < 16; p++) {
            int orow = ty * 16 + p;
            outp[(size_t)(c0 + orow) * R + r0 + tx] = f_to_fp8(t[tx][orow]);
        }
        return;
    }

    // conv: segments fp32 -> segF8 fp8 (8 elems/thread)
    {
        long i = (long)(bid - PR_TR2E) * 256 + tid;
        const float4* in = (const float4*)segments;
        float4 a = in[2 * i], b = in[2 * i + 1];
        unsigned int lo = f4_to_fp8x4(a.x, a.y, a.z, a.w);
        unsigned int hi = f4_to_fp8x4(b.x, b.y, b.z, b.w);
        *(uint2*)(segF8 + i * 8) = make_uint2(lo, hi);
    }
}

// ---------------- fp8 MX-scaled MFMA GEMM ----------------
// C[M,N] = gelu(A8[M,K] @ Bt8[N,K]^T + bias + optional sum qW1p[bag])
// MODE 1: output fp8 bytes to global (K2)
// MODE 2: fuse W3 GEMV: output partial preds fp32 [gridDim.x][M][4] (K3)
// 128x128 block, 4 waves, wave 64x64 = 2x2 of 32x32x64 f8f6f4 (unit scales).
// Double-buffered staging (2x16KB), 1 barrier per K-step, prefetch issue-early.
template<int MODE>
__global__ __launch_bounds__(256) void mfma_gemm_f8(
    const unsigned char* __restrict__ A8,    // [M,K] fp8
    const unsigned char* __restrict__ Bt8,   // [N,K] fp8
    const float* __restrict__ bias,          // [N]
    const float* __restrict__ rowAdd,        // [8][128,N] partials or null
    void* __restrict__ CoutV,                // [M,N] fp8, or [gx][M][4] f32
    int M, int N, int K,
    const float* __restrict__ W3p)           // [N][4] (MODE 2 only)
{
    __shared__ __align__(16) unsigned char smem8[32768 + (MODE == 2 ? 2048 : 0)];
    const int tid = threadIdx.x;
    const int wave = tid >> 6, lane = tid & 63;

    // T1: bijective XCD-chunked swizzle (nwg % 8 == 0 for both grids)
    const int nwg = gridDim.x * gridDim.y;
    const int bidl = blockIdx.y * gridDim.x + blockIdx.x;
    const int cpx = nwg >> 3;
    const int swz = (bidl & 7) * cpx + (bidl >> 3);
    const int m0 = (swz / gridDim.x) * 128, n0 = (swz % gridDim.x) * 128;
    const int wm = (wave & 1) * 64, wn = (wave >> 1) * 64;

    if constexpr (MODE == 2) {
        // stash W3 chunk for this n-tile (cols n0..n0+127) beyond the dbuf region
        if (tid < 128)
            ((float4*)(smem8 + 32768))[tid] = ((const float4*)W3p)[n0 + tid];
    }

    f32x16 acc[2][2] = {};

    const int srow = tid >> 2;
    const int schunk = (tid & 3) ^ ((srow >> 1) & 3);
    const unsigned char* Ag = A8 + (size_t)(m0 + srow) * K + schunk * 16;
    const unsigned char* Bg = Bt8 + (size_t)(n0 + srow) * K + schunk * 16;

    const int fm = lane & 31, fq = lane >> 5;

#define STAGE_K(buf, kk) do {                                   \
        unsigned char* _d = smem8 + (buf) * 16384 + tid * 16;   \
        g2l16(Ag + (kk), _d);                                   \
        g2l16(Ag + (size_t)64 * K + (kk), _d + 4096);           \
        g2l16(Bg + (kk), _d + 8192);                            \
        g2l16(Bg + (size_t)64 * K + (kk), _d + 12288);          \
    } while (0)

    STAGE_K(0, 0);
    __syncthreads();              // drains vmcnt(0): buf0 ready
    int cur = 0;
    for (int k0 = 0; k0 < K; k0 += 64) {
        if (k0 + 64 < K) STAGE_K(cur ^ 1, k0 + 64);   // prefetch flies under MFMA

        const unsigned char* As = smem8 + cur * 16384;
        const unsigned char* Bs = As + 8192;
        i32x8 av[2], bv[2];
        #pragma unroll
        for (int i = 0; i < 2; i++) {
            int rw = wm + i * 32 + fm, key = (rw >> 1) & 3;
            i32x4 lo = *(const i32x4*)&As[rw * 64 + (((fq << 1) | 0) ^ key) * 16];
            i32x4 hi = *(const i32x4*)&As[rw * 64 + (((fq << 1) | 1) ^ key) * 16];
            av[i][0] = lo[0]; av[i][1] = lo[1]; av[i][2] = lo[2]; av[i][3] = lo[3];
            av[i][4] = hi[0]; av[i][5] = hi[1]; av[i][6] = hi[2]; av[i][7] = hi[3];
        }
        #pragma unroll
        for (int j = 0; j < 2; j++) {
            int rw = wn + j * 32 + fm, key = (rw >> 1) & 3;
            i32x4 lo = *(const i32x4*)&Bs[rw * 64 + (((fq << 1) | 0) ^ key) * 16];
            i32x4 hi = *(const i32x4*)&Bs[rw * 64 + (((fq << 1) | 1) ^ key) * 16];
            bv[j][0] = lo[0]; bv[j][1] = lo[1]; bv[j][2] = lo[2]; bv[j][3] = lo[3];
            bv[j][4] = hi[0]; bv[j][5] = hi[1]; bv[j][6] = hi[2]; bv[j][7] = hi[3];
        }
        #pragma unroll
        for (int i = 0; i < 2; i++)
            #pragma unroll
            for (int j = 0; j < 2; j++)
                acc[i][j] = __builtin_amdgcn_mfma_scale_f32_32x32x64_f8f6f4(
                    av[i], bv[j], acc[i][j], 0, 0,   // cbsz=fp8, blgp=fp8
                    0, 127, 0, 127);                 // unit e8m0 scales
        __syncthreads();           // vmcnt(0) drain lands AFTER compute
        cur ^= 1;
    }
#undef STAGE_K

    // Epilogue (C/D: col=lane&31, row=(reg&3)+8*(reg>>2)+4*(lane>>5)), gelu
    #pragma unroll
    for (int j = 0; j < 2; j++) {
        int coll = wn + j * 32 + fm;
        int col = n0 + coll;
        float add = bias[col];
        if (rowAdd) {
            const float* radd = rowAdd + (size_t)(m0 >> 8) * N + col;
            #pragma unroll
            for (int s = 0; s < 8; s++) add += radd[(size_t)s * 98304];
        }
        #pragma unroll
        for (int i = 0; i < 2; i++) {
            int rbase = wm + i * 32 + 4 * fq;
            #pragma unroll
            for (int reg = 0; reg < 16; reg++) {
                int rowl = rbase + (reg & 3) + 8 * (reg >> 2);
                float v = gelu_fast(acc[i][j][reg] + add);
                if constexpr (MODE == 1) smem8[rowl * 128 + coll] = f_to_fp8(v);
                else ((unsigned short*)smem8)[rowl * 128 + coll] = f2bf(v);
            }
        }
    }
    __syncthreads();
    if constexpr (MODE == 1) {
        unsigned char* Cout = (unsigned char*)CoutV;
        #pragma unroll
        for (int it = 0; it < 4; it++) {
            int idx = it * 256 + tid;
            int r = idx >> 3, cc = (idx & 7) * 16;
            *(uint4*)&Cout[(size_t)(m0 + r) * N + n0 + cc] =
                *(const uint4*)&smem8[r * 128 + cc];
        }
    } else if constexpr (MODE == 2) {
        // per-row GEMV with the W3 chunk: 2 threads/row, 64 cols each.
        // XOR the chunk order with (r&7) to spread the 256B-stride rows
        // across banks (avoids a 32-way conflict on b128 LDS reads).
        const float4* w3sh = (const float4*)(smem8 + 32768);
        const unsigned short* tile = (const unsigned short*)smem8;
        int r = tid >> 1, ch = tid & 1;
        const unsigned short* rowp = tile + r * 128 + ch * 64;
        float4 a = make_float4(0.f, 0.f, 0.f, 0.f);
        #pragma unroll
        for (int k = 0; k < 8; k++) {
            int kk = k ^ (r & 7);
            ushort8 u = *(const ushort8*)(rowp + kk * 8);
            #pragma unroll
            for (int jj = 0; jj < 8; jj++) {
                float h = bf2f(u[jj]);
                float4 wv2 = w3sh[ch * 64 + kk * 8 + jj];
                a.x += h * wv2.x; a.y += h * wv2.y;
                a.z += h * wv2.z; a.w += h * wv2.w;
            }
        }
        a.x += __shfl_xor(a.x, 1); a.y += __shfl_xor(a.y, 1);
        a.z += __shfl_xor(a.z, 1); a.w += __shfl_xor(a.w, 1);
        if (ch == 0)
            ((float4*)CoutV)[(size_t)(n0 >> 7) * 32768 + m0 + r] = a;
    }
}

// ---------------- head: softmax + aggregation over partial preds ----------------
__device__ __forceinline__ float4 f4mul(float4 a, float4 b) {
    return make_float4(a.x * b.x, a.y * b.y, a.z * b.z, a.w * b.w);
}

// block-wide inclusive product-scan of 256 float4 via wave shfl scans.
__device__ __forceinline__ float4 block_scan_prod(float4 v, int lane, int wv,
                                                  float4* wtot) {
    #pragma unroll
    for (int off = 1; off < 64; off <<= 1) {
        float4 t;
        t.x = __shfl_up(v.x, off); t.y = __shfl_up(v.y, off);
        t.z = __shfl_up(v.z, off); t.w = __shfl_up(v.w, off);
        if (lane >= off) v = f4mul(v, t);
    }
    if (lane == 63) wtot[wv] = v;
    __syncthreads();
    float4 pre = make_float4(1.f, 1.f, 1.f, 1.f);
    #pragma unroll
    for (int w = 0; w < 3; w++)
        if (w < wv) pre = f4mul(pre, wtot[w]);
    __syncthreads();
    return f4mul(pre, v);
}

__global__ __launch_bounds__(256) void head_kernel(
    const float* __restrict__ pp,   // [3][32768][4] partial preds
    const float* __restrict__ b3,
    const int* __restrict__ nseg,
    float* __restrict__ out)
{
    __shared__ float4 xbuf[256];
    __shared__ float4 wtot[4];
    const int b = blockIdx.x, tid = threadIdx.x;
    const int lane = tid & 63, wv = tid >> 6;
    const float4 ones = make_float4(1.f, 1.f, 1.f, 1.f);

    const float4* ppv = (const float4*)pp;
    size_t row = (size_t)b * 256 + tid;
    float4 a0 = ppv[row], a1 = ppv[row + 32768], a2 = ppv[row + 65536];
    float4 acc = make_float4(a0.x + a1.x + a2.x + b3[0],
                             a0.y + a1.y + a2.y + b3[1],
                             a0.z + a1.z + a2.z + b3[2],
                             a0.w + a1.w + a2.w + b3[3]);
    float m = fmaxf(fmaxf(acc.x, acc.y), fmaxf(acc.z, acc.w));
    float e0 = __expf(acc.x - m), e1 = __expf(acc.y - m),
          e2 = __expf(acc.z - m), e3 = __expf(acc.w - m);
    float inv = 1.0f / (e0 + e1 + e2 + e3);
    float4 p = make_float4(e0 * inv, e1 * inv, e2 * inv, e3 * inv);

    const int n = nseg[b];
    bool msk = tid < n;
    float s1 = p.x, s2 = s1 + p.y, s3 = s2 + p.z;
    float4 sm = msk ? make_float4(0.f, s1, s2, s3) : ones;

    // inclusive prefix scan -> exclusive prefix pfx
    float4 isc = block_scan_prod(sm, lane, wv, wtot);
    xbuf[tid] = isc;
    __syncthreads();
    float4 pfx = (tid > 0) ? xbuf[tid - 1] : ones;
    __syncthreads();

    // reversed scan -> exclusive suffix sfx
    xbuf[255 - tid] = sm;
    __syncthreads();
    float4 rsm = xbuf[tid];
    __syncthreads();
    float4 risc = block_scan_prod(rsm, lane, wv, wtot);
    xbuf[tid] = risc;
    __syncthreads();
    float4 sfx = (tid < 255) ? xbuf[254 - tid] : ones;
    __syncthreads();

    float4 L = f4mul(pfx, sfx);        // leave-one-out products
    float4 cpL = block_scan_prod(L, lane, wv, wtot);

    float4 term = msk ? f4mul(p, cpL) : make_float4(0.f, 0.f, 0.f, 0.f);
    float4 pm = msk ? p : ones;
    #pragma unroll
    for (int off = 32; off > 0; off >>= 1) {
        term.x += __shfl_xor(term.x, off); term.y += __shfl_xor(term.y, off);
        term.z += __shfl_xor(term.z, off); term.w += __shfl_xor(term.w, off);
        pm.x *= __shfl_xor(pm.x, off); pm.y *= __shfl_xor(pm.y, off);
        pm.z *= __shfl_xor(pm.z, off); pm.w *= __shfl_xor(pm.w, off);
    }
    if (lane == 0) { xbuf[wv] = term; xbuf[4 + wv] = pm; }
    __syncthreads();
    if (tid == 0) {
        float4 st = make_float4(0.f, 0.f, 0.f, 0.f);
        float4 pr = ones;
        #pragma unroll
        for (int w = 0; w < 4; w++) {
            float4 t = xbuf[w], q = xbuf[4 + w];
            st.x += t.x; st.y += t.y; st.z += t.z; st.w += t.w;
            pr = f4mul(pr, q);
        }
        ((float4*)out)[b] = make_float4(0.25f * st.x + pr.x,
                                        0.25f * st.y + pr.y,
                                        0.25f * st.z + pr.z,
                                        0.25f * st.w + pr.w);
    }
}

extern "C" void kernel_launch(void* const* d_in, const int* in_sizes, int n_in,
                              void* d_out, int out_size, void* d_ws, size_t ws_size,
                              hipStream_t stream) {
    (void)in_sizes; (void)n_in; (void)out_size; (void)ws_size;
    const float* questions = (const float*)d_in[0];
    const float* segments  = (const float*)d_in[1];
    const float* W1 = (const float*)d_in[2];
    const float* b1 = (const float*)d_in[3];
    const float* W2 = (const float*)d_in[4];
    const float* b2 = (const float*)d_in[5];
    const float* W3 = (const float*)d_in[6];
    const float* b3 = (const float*)d_in[7];
    const int*  nseg = (const int*)d_in[8];
    float* out = (float*)d_out;

    char* w = (char*)d_ws;
    float* qW1p = (float*)w;                   w += (size_t)8 * 128 * 768 * 4;
    unsigned char*  W1t8 = (unsigned char*)w;  w += (size_t)768 * 768;
    unsigned char*  W2t8 = (unsigned char*)w;  w += (size_t)384 * 768;
    unsigned char*  segF8 = (unsigned char*)w; w += (size_t)32768 * 768;
    unsigned char*  H1f8 = (unsigned char*)w;  w += (size_t)32768 * 768;
    float* ppreds = (float*)w;                 w += (size_t)3 * 32768 * 4 * 4;

    prep_rest_kernel<<<PR_END, 256, 0, stream>>>(
        segments, segF8, W1, W1t8, W2, W2t8);
    prep_q_kernel<<<96, 256, 0, stream>>>(questions, W1, qW1p);
    // K2 (fp8 -> fp8): grid (n=6, m=256)
    mfma_gemm_f8<1><<<dim3(6, 256), 256, 0, stream>>>(
        segF8, W1t8, b1, qW1p, H1f8, 32768, 768, 768, nullptr);
    // K3 (fp8 -> fused W3 partial preds): grid (n=3, m=256)
    mfma_gemm_f8<2><<<dim3(3, 256), 256, 0, stream>>>(
        H1f8, W2t8, b2, nullptr, ppreds, 32768, 384, 768, W3);
    head_kernel<<<128, 256, 0, stream>>>(ppreds, b3, nseg, out);
}

// Round 3
// 229.614 us; speedup vs baseline: 1.1024x; 1.1024x over previous
//
#include <hip/hip_runtime.h>
#include <hip/hip_bf16.h>

// B=128, S=256, E=768, C=4; M = B*S = 32768.
// R1 kernel + nseg-aware dead-block elision:
//  - prep conversion blocks skip fully-masked rows (saves ~half the 128MB segments read)
//  - K2/K3 m-blocks (one bag-half each) exit early when nseg[bag] <= rows covered
//  Dead rows carry poison (possibly fp8-NaN) but the head select-masks them, and
//  MFMA NaN is confined per-output-row, so nothing propagates to live outputs.
// 4 launches: prep | K2 (fp8-MX MFMA) | K3 (fused W3 GEMV epilogue) | head.

typedef __attribute__((ext_vector_type(8))) short short8;
typedef __attribute__((ext_vector_type(8))) unsigned short ushort8;
typedef __attribute__((ext_vector_type(16))) float f32x16;
typedef __attribute__((ext_vector_type(8))) int i32x8;
typedef __attribute__((ext_vector_type(4))) int i32x4;

__device__ __forceinline__ unsigned short f2bf(float f) {
    union { float f; unsigned int u; } c; c.f = f;
    unsigned int u = c.u;
    unsigned int r = (u + 0x7FFFu + ((u >> 16) & 1u)) >> 16;  // RNE
    return (unsigned short)r;
}
__device__ __forceinline__ float bf2f(unsigned short u) {
    union { unsigned int u; float f; } c; c.u = ((unsigned int)u) << 16;
    return c.f;
}
__device__ __forceinline__ float gelu_fast(float x) {
    float x2 = x * x;
    float y2 = 1.5957691216057308f * (x + 0.044715f * x2 * x);
    float e = __expf(y2);
    float t = 1.0f - 2.0f * __builtin_amdgcn_rcpf(e + 1.0f);
    return 0.5f * x * (1.0f + t);
}

typedef const __attribute__((address_space(1))) void* gas_t;
typedef __attribute__((address_space(3))) void* las_t;
__device__ __forceinline__ void g2l16(const void* g, void* l) {
    __builtin_amdgcn_global_load_lds((gas_t)g, (las_t)l, 16, 0, 0);
}

// pack 4 floats -> 4 fp8 e4m3 bytes (RNE, saturating)
__device__ __forceinline__ unsigned int f4_to_fp8x4(float a, float b, float c, float d) {
    int lo = __builtin_amdgcn_cvt_pk_fp8_f32(a, b, 0, 0);
    return (unsigned int)__builtin_amdgcn_cvt_pk_fp8_f32(c, d, lo, 1);
}
__device__ __forceinline__ unsigned char f_to_fp8(float a) {
    return (unsigned char)(__builtin_amdgcn_cvt_pk_fp8_f32(a, a, 0, 0) & 0xFF);
}

// ---------------- fused prep kernel ----------------
#define PREP_Q    96
#define PREP_TR1E 240
#define PREP_TR2E 312
#define PREP_END  12600

__global__ __launch_bounds__(256) void prep_kernel(
    const float* __restrict__ segments, unsigned char* __restrict__ segF8,
    const float* __restrict__ W1, unsigned char* __restrict__ W1t8,
    const float* __restrict__ W2, unsigned char* __restrict__ W2t8,
    const float* __restrict__ questions, float* __restrict__ qW1p,
    const int* __restrict__ nseg)
{
    __shared__ __align__(16) char sh[16640];
    const int bid = blockIdx.x, tid = threadIdx.x;

    if (bid < PREP_Q) {
        const int s = bid / 24, rem = bid % 24;
        const int n0 = (rem % 12) * 64, m0 = (rem / 12) * 64;
        float (*As)[64] = (float(*)[64])sh;
        float (*Bs)[64] = (float(*)[64])(sh + 4096);
        const int tn = tid & 15, tm = tid >> 4;
        float acc[4][4] = {};
        const int la_m = tid >> 2;
        const int la_k = (tid & 3) << 2;
        const int lb_k = tid >> 4;
        const int lb_n = (tid & 15) << 2;
        const float* Aptr = questions + (size_t)(m0 + la_m) * 768 + la_k;
        const float* Bptr = W1 + (size_t)lb_k * 768 + n0 + lb_n;
        const int kbeg = s * 192, kend = kbeg + 192;
        for (int k0 = kbeg; k0 < kend; k0 += 16) {
            float4 av = *(const float4*)(Aptr + k0);
            float4 bv = *(const float4*)(Bptr + (size_t)k0 * 768);
            As[la_k + 0][la_m] = av.x;
            As[la_k + 1][la_m] = av.y;
            As[la_k + 2][la_m] = av.z;
            As[la_k + 3][la_m] = av.w;
            *(float4*)&Bs[lb_k][lb_n] = bv;
            __syncthreads();
            #pragma unroll
            for (int k = 0; k < 16; k++) {
                float4 a = *(const float4*)&As[k][tm << 2];
                float4 b = *(const float4*)&Bs[k][tn << 2];
                float ar[4] = {a.x, a.y, a.z, a.w};
                float br[4] = {b.x, b.y, b.z, b.w};
                #pragma unroll
                for (int i = 0; i < 4; i++)
                    #pragma unroll
                    for (int j = 0; j < 4; j++)
                        acc[i][j] += ar[i] * br[j];
            }
            __syncthreads();
        }
        float* outp = qW1p + (size_t)s * 128 * 768;
        #pragma unroll
        for (int i = 0; i < 4; i++) {
            int row = m0 + (tm << 2) + i;
            int colBase = n0 + (tn << 2);
            *(float4*)&outp[(size_t)row * 768 + colBase] =
                make_float4(acc[i][0], acc[i][1], acc[i][2], acc[i][3]);
        }
        return;
    }

    if (bid < PREP_TR2E) {
        // transpose 64x64 tile -> fp8 bytes
        const float* in; unsigned char* outp; int R, C, bx, by;
        if (bid < PREP_TR1E) {
            int idx = bid - PREP_Q; bx = idx % 12; by = idx / 12;
            in = W1 + 768 * 768; outp = W1t8; R = 768; C = 768;
        } else {
            int idx = bid - PREP_TR1E; bx = idx % 6; by = idx / 6;
            in = W2; outp = W2t8; R = 768; C = 384;
        }
        float (*t)[65] = (float(*)[65])sh;
        int r0 = by * 64, c0 = bx * 64;
        int tx = tid & 63, ty = tid >> 6;
        #pragma unroll
        for (int p = 0; p < 16; p++) {
            int row = ty * 16 + p;
            t[row][tx] = in[(size_t)(r0 + row) * C + c0 + tx];
        }
        __syncthreads();
        #pragma unroll
        for (int p = 0; p < 16; p++) {
            int orow = ty * 16 + p;
            outp[(size_t)(c0 + orow) * R + r0 + tx] = f_to_fp8(t[tx][orow]);
        }
        return;
    }

    // conv: segments fp32 -> segF8 fp8 (8 elems/thread, 2048 elems/block).
    // 196608 elems/bag is a multiple of 2048 -> each block is within ONE bag.
    // Skip blocks whose rows are all masked (row_in_bag >= nseg[bag]).
    {
        int cb = bid - PREP_TR2E;
        int row0 = (cb * 2048) / 768;           // first segment-row this block touches
        if ((row0 & 255) >= nseg[row0 >> 8]) return;
        long i = (long)cb * 256 + tid;
        const float4* in = (const float4*)segments;
        float4 a = in[2 * i], b = in[2 * i + 1];
        unsigned int lo = f4_to_fp8x4(a.x, a.y, a.z, a.w);
        unsigned int hi = f4_to_fp8x4(b.x, b.y, b.z, b.w);
        *(uint2*)(segF8 + i * 8) = make_uint2(lo, hi);
    }
}

// ---------------- fp8 MX-scaled MFMA GEMM ----------------
// C[M,N] = gelu(A8[M,K] @ Bt8[N,K]^T + bias + optional sum qW1p[bag])
// MODE 1: output fp8 bytes to global (K2)
// MODE 2: fuse W3 GEMV: output partial preds fp32 [gridDim.x][M][4] (K3)
// 128x128 block, 4 waves, wave 64x64 = 2x2 of 32x32x64 f8f6f4 (unit scales).
// Each m-block covers one 128-row bag-half; exits if those rows are all masked.
template<int MODE>
__global__ __launch_bounds__(256) void mfma_gemm_f8(
    const unsigned char* __restrict__ A8,    // [M,K] fp8
    const unsigned char* __restrict__ Bt8,   // [N,K] fp8
    const float* __restrict__ bias,          // [N]
    const float* __restrict__ rowAdd,        // [4][128,N] partials or null
    void* __restrict__ CoutV,                // [M,N] fp8, or [gx][M][4] f32
    int M, int N, int K,
    const float* __restrict__ W3p,           // [N][4] (MODE 2 only)
    const int* __restrict__ nseg)
{
    __shared__ __align__(16) unsigned char smem8[32768 + (MODE == 2 ? 2048 : 0)];
    unsigned char* As = smem8;             // [128][64B] swizzled (8KB)
    unsigned char* Bs = smem8 + 8192;      // [128][64B] (8KB)
    const int tid = threadIdx.x;
    const int wave = tid >> 6, lane = tid & 63;
    const int m0 = blockIdx.y * 128, n0 = blockIdx.x * 128;

    // dead bag-half elision: rows [m0&255, (m0&255)+128) of bag m0>>8
    if (nseg[m0 >> 8] <= (m0 & 255)) return;

    const int wm = (wave & 1) * 64, wn = (wave >> 1) * 64;

    if constexpr (MODE == 2) {
        // stash W3 chunk for this n-tile (cols n0..n0+127) beyond the tile buffer
        if (tid < 128)
            ((float4*)(smem8 + 32768))[tid] = ((const float4*)W3p)[n0 + tid];
    }

    f32x16 acc[2][2] = {};

    const int srow = tid >> 2;
    const int schunk = (tid & 3) ^ ((srow >> 1) & 3);
    const unsigned char* Ag = A8 + (size_t)(m0 + srow) * K + schunk * 16;
    const unsigned char* Bg = Bt8 + (size_t)(n0 + srow) * K + schunk * 16;
    unsigned char* Al = As + tid * 16;
    unsigned char* Bl = Bs + tid * 16;

    const int fm = lane & 31, fq = lane >> 5;

    for (int k0 = 0; k0 < K; k0 += 64) {
        g2l16(Ag + k0, Al);
        g2l16(Ag + (size_t)64 * K + k0, Al + 4096);
        g2l16(Bg + k0, Bl);
        g2l16(Bg + (size_t)64 * K + k0, Bl + 4096);
        __syncthreads();

        i32x8 av[2], bv[2];
        #pragma unroll
        for (int i = 0; i < 2; i++) {
            int rw = wm + i * 32 + fm, key = (rw >> 1) & 3;
            i32x4 lo = *(const i32x4*)&As[rw * 64 + (((fq << 1) | 0) ^ key) * 16];
            i32x4 hi = *(const i32x4*)&As[rw * 64 + (((fq << 1) | 1) ^ key) * 16];
            av[i][0] = lo[0]; av[i][1] = lo[1]; av[i][2] = lo[2]; av[i][3] = lo[3];
            av[i][4] = hi[0]; av[i][5] = hi[1]; av[i][6] = hi[2]; av[i][7] = hi[3];
        }
        #pragma unroll
        for (int j = 0; j < 2; j++) {
            int rw = wn + j * 32 + fm, key = (rw >> 1) & 3;
            i32x4 lo = *(const i32x4*)&Bs[rw * 64 + (((fq << 1) | 0) ^ key) * 16];
            i32x4 hi = *(const i32x4*)&Bs[rw * 64 + (((fq << 1) | 1) ^ key) * 16];
            bv[j][0] = lo[0]; bv[j][1] = lo[1]; bv[j][2] = lo[2]; bv[j][3] = lo[3];
            bv[j][4] = hi[0]; bv[j][5] = hi[1]; bv[j][6] = hi[2]; bv[j][7] = hi[3];
        }
        #pragma unroll
        for (int i = 0; i < 2; i++)
            #pragma unroll
            for (int j = 0; j < 2; j++)
                acc[i][j] = __builtin_amdgcn_mfma_scale_f32_32x32x64_f8f6f4(
                    av[i], bv[j], acc[i][j], 0, 0,   // cbsz=fp8, blgp=fp8
                    0, 127, 0, 127);                 // unit e8m0 scales
        __syncthreads();
    }

    // Epilogue (C/D: col=lane&31, row=(reg&3)+8*(reg>>2)+4*(lane>>5)), gelu
    #pragma unroll
    for (int j = 0; j < 2; j++) {
        int coll = wn + j * 32 + fm;
        int col = n0 + coll;
        float add = bias[col];
        if (rowAdd) {
            const float* radd = rowAdd + (size_t)(m0 >> 8) * N;
            add += radd[col] + radd[col + 98304] +
                   radd[col + 2 * 98304] + radd[col + 3 * 98304];
        }
        #pragma unroll
        for (int i = 0; i < 2; i++) {
            int rbase = wm + i * 32 + 4 * fq;
            #pragma unroll
            for (int reg = 0; reg < 16; reg++) {
                int rowl = rbase + (reg & 3) + 8 * (reg >> 2);
                float v = gelu_fast(acc[i][j][reg] + add);
                if constexpr (MODE == 1) smem8[rowl * 128 + coll] = f_to_fp8(v);
                else ((unsigned short*)smem8)[rowl * 128 + coll] = f2bf(v);
            }
        }
    }
    __syncthreads();
    if constexpr (MODE == 1) {
        unsigned char* Cout = (unsigned char*)CoutV;
        #pragma unroll
        for (int it = 0; it < 4; it++) {
            int idx = it * 256 + tid;
            int r = idx >> 3, cc = (idx & 7) * 16;
            *(uint4*)&Cout[(size_t)(m0 + r) * N + n0 + cc] =
                *(const uint4*)&smem8[r * 128 + cc];
        }
    } else if constexpr (MODE == 2) {
        // per-row GEMV with the W3 chunk: 2 threads/row, 64 cols each.
        // XOR the chunk order with (r&7) to spread the 256B-stride rows
        // across banks (avoids a 32-way conflict on b128 LDS reads).
        const float4* w3sh = (const float4*)(smem8 + 32768);
        const unsigned short* tile = (const unsigned short*)smem8;
        int r = tid >> 1, ch = tid & 1;
        const unsigned short* rowp = tile + r * 128 + ch * 64;
        float4 a = make_float4(0.f, 0.f, 0.f, 0.f);
        #pragma unroll
        for (int k = 0; k < 8; k++) {
            int kk = k ^ (r & 7);
            ushort8 u = *(const ushort8*)(rowp + kk * 8);
            #pragma unroll
            for (int jj = 0; jj < 8; jj++) {
                float h = bf2f(u[jj]);
                float4 wv2 = w3sh[ch * 64 + kk * 8 + jj];
                a.x += h * wv2.x; a.y += h * wv2.y;
                a.z += h * wv2.z; a.w += h * wv2.w;
            }
        }
        // combine the two column-halves (lanes 2r, 2r+1 are wave-adjacent)
        a.x += __shfl_xor(a.x, 1); a.y += __shfl_xor(a.y, 1);
        a.z += __shfl_xor(a.z, 1); a.w += __shfl_xor(a.w, 1);
        if (ch == 0)
            ((float4*)CoutV)[(size_t)blockIdx.x * 32768 + m0 + r] = a;
    }
}

// ---------------- head: softmax + aggregation over partial preds ----------------
__device__ __forceinline__ float4 f4mul(float4 a, float4 b) {
    return make_float4(a.x * b.x, a.y * b.y, a.z * b.z, a.w * b.w);
}

// block-wide inclusive product-scan of 256 float4 via wave shfl scans.
__device__ __forceinline__ float4 block_scan_prod(float4 v, int lane, int wv,
                                                  float4* wtot) {
    #pragma unroll
    for (int off = 1; off < 64; off <<= 1) {
        float4 t;
        t.x = __shfl_up(v.x, off); t.y = __shfl_up(v.y, off);
        t.z = __shfl_up(v.z, off); t.w = __shfl_up(v.w, off);
        if (lane >= off) v = f4mul(v, t);
    }
    if (lane == 63) wtot[wv] = v;
    __syncthreads();
    float4 pre = make_float4(1.f, 1.f, 1.f, 1.f);
    #pragma unroll
    for (int w = 0; w < 3; w++)
        if (w < wv) pre = f4mul(pre, wtot[w]);
    __syncthreads();
    return f4mul(pre, v);
}

__global__ __launch_bounds__(256) void head_kernel(
    const float* __restrict__ pp,   // [3][32768][4] partial preds
    const float* __restrict__ b3,
    const int* __restrict__ nseg,
    float* __restrict__ out)
{
    __shared__ float4 xbuf[256];
    __shared__ float4 wtot[4];
    const int b = blockIdx.x, tid = threadIdx.x;
    const int lane = tid & 63, wv = tid >> 6;
    const float4 ones = make_float4(1.f, 1.f, 1.f, 1.f);

    const float4* ppv = (const float4*)pp;
    size_t row = (size_t)b * 256 + tid;
    float4 a0 = ppv[row], a1 = ppv[row + 32768], a2 = ppv[row + 65536];
    float4 acc = make_float4(a0.x + a1.x + a2.x + b3[0],
                             a0.y + a1.y + a2.y + b3[1],
                             a0.z + a1.z + a2.z + b3[2],
                             a0.w + a1.w + a2.w + b3[3]);
    float m = fmaxf(fmaxf(acc.x, acc.y), fmaxf(acc.z, acc.w));
    float e0 = __expf(acc.x - m), e1 = __expf(acc.y - m),
          e2 = __expf(acc.z - m), e3 = __expf(acc.w - m);
    float inv = 1.0f / (e0 + e1 + e2 + e3);
    float4 p = make_float4(e0 * inv, e1 * inv, e2 * inv, e3 * inv);

    const int n = nseg[b];
    bool msk = tid < n;
    float s1 = p.x, s2 = s1 + p.y, s3 = s2 + p.z;
    float4 sm = msk ? make_float4(0.f, s1, s2, s3) : ones;

    // inclusive prefix scan -> exclusive prefix pfx
    float4 isc = block_scan_prod(sm, lane, wv, wtot);
    xbuf[tid] = isc;
    __syncthreads();
    float4 pfx = (tid > 0) ? xbuf[tid - 1] : ones;
    __syncthreads();

    // reversed scan -> exclusive suffix sfx
    xbuf[255 - tid] = sm;
    __syncthreads();
    float4 rsm = xbuf[tid];
    __syncthreads();
    float4 risc = block_scan_prod(rsm, lane, wv, wtot);
    xbuf[tid] = risc;
    __syncthreads();
    float4 sfx = (tid < 255) ? xbuf[254 - tid] : ones;
    __syncthreads();

    float4 L = f4mul(pfx, sfx);        // leave-one-out products
    float4 cpL = block_scan_prod(L, lane, wv, wtot);

    float4 term = msk ? f4mul(p, cpL) : make_float4(0.f, 0.f, 0.f, 0.f);
    float4 pm = msk ? p : ones;
    #pragma unroll
    for (int off = 32; off > 0; off >>= 1) {
        term.x += __shfl_xor(term.x, off); term.y += __shfl_xor(term.y, off);
        term.z += __shfl_xor(term.z, off); term.w += __shfl_xor(term.w, off);
        pm.x *= __shfl_xor(pm.x, off); pm.y *= __shfl_xor(pm.y, off);
        pm.z *= __shfl_xor(pm.z, off); pm.w *= __shfl_xor(pm.w, off);
    }
    if (lane == 0) { xbuf[wv] = term; xbuf[4 + wv] = pm; }
    __syncthreads();
    if (tid == 0) {
        float4 st = make_float4(0.f, 0.f, 0.f, 0.f);
        float4 pr = ones;
        #pragma unroll
        for (int w = 0; w < 4; w++) {
            float4 t = xbuf[w], q = xbuf[4 + w];
            st.x += t.x; st.y += t.y; st.z += t.z; st.w += t.w;
            pr = f4mul(pr, q);
        }
        ((float4*)out)[b] = make_float4(0.25f * st.x + pr.x,
                                        0.25f * st.y + pr.y,
                                        0.25f * st.z + pr.z,
                                        0.25f * st.w + pr.w);
    }
}

extern "C" void kernel_launch(void* const* d_in, const int* in_sizes, int n_in,
                              void* d_out, int out_size, void* d_ws, size_t ws_size,
                              hipStream_t stream) {
    (void)in_sizes; (void)n_in; (void)out_size; (void)ws_size;
    const float* questions = (const float*)d_in[0];
    const float* segments  = (const float*)d_in[1];
    const float* W1 = (const float*)d_in[2];
    const float* b1 = (const float*)d_in[3];
    const float* W2 = (const float*)d_in[4];
    const float* b2 = (const float*)d_in[5];
    const float* W3 = (const float*)d_in[6];
    const float* b3 = (const float*)d_in[7];
    const int*  nseg = (const int*)d_in[8];
    float* out = (float*)d_out;

    char* w = (char*)d_ws;
    float* qW1p = (float*)w;                   w += (size_t)4 * 128 * 768 * 4;
    unsigned char*  W1t8 = (unsigned char*)w;  w += (size_t)768 * 768;
    unsigned char*  W2t8 = (unsigned char*)w;  w += (size_t)384 * 768;
    unsigned char*  segF8 = (unsigned char*)w; w += (size_t)32768 * 768;
    unsigned char*  H1f8 = (unsigned char*)w;  w += (size_t)32768 * 768;
    float* ppreds = (float*)w;                 w += (size_t)3 * 32768 * 4 * 4;

    prep_kernel<<<PREP_END, 256, 0, stream>>>(
        segments, segF8, W1, W1t8, W2, W2t8, questions, qW1p, nseg);
    // K2 (fp8 -> fp8): grid (n=6, m=256)
    mfma_gemm_f8<1><<<dim3(6, 256), 256, 0, stream>>>(
        segF8, W1t8, b1, qW1p, H1f8, 32768, 768, 768, nullptr, nseg);
    // K3 (fp8 -> fused W3 partial preds): grid (n=3, m=256)
    mfma_gemm_f8<2><<<dim3(3, 256), 256, 0, stream>>>(
        H1f8, W2t8, b2, nullptr, ppreds, 32768, 384, 768, W3, nseg);
    head_kernel<<<128, 256, 0, stream>>>(ppreds, b3, nseg, out);
}

// Round 4
// 228.577 us; speedup vs baseline: 1.1074x; 1.0045x over previous
//
#include <hip/hip_runtime.h>
#include <hip/hip_bf16.h>

// B=128, S=256, E=768, C=4; M = B*S = 32768.
// R3 kernel + q-GEMM branch rewritten: 64-wide K staging (LDS 2x[64][68] f32),
// 6 barriers per block instead of 384, bank-clean transposed A staging.
// Everything else identical to R3 (elision in prep-conv and K2/K3 m-blocks).
// 4 launches: prep | K2 (fp8-MX MFMA) | K3 (fused W3 GEMV epilogue) | head.

typedef __attribute__((ext_vector_type(8))) short short8;
typedef __attribute__((ext_vector_type(8))) unsigned short ushort8;
typedef __attribute__((ext_vector_type(16))) float f32x16;
typedef __attribute__((ext_vector_type(8))) int i32x8;
typedef __attribute__((ext_vector_type(4))) int i32x4;

__device__ __forceinline__ unsigned short f2bf(float f) {
    union { float f; unsigned int u; } c; c.f = f;
    unsigned int u = c.u;
    unsigned int r = (u + 0x7FFFu + ((u >> 16) & 1u)) >> 16;  // RNE
    return (unsigned short)r;
}
__device__ __forceinline__ float bf2f(unsigned short u) {
    union { unsigned int u; float f; } c; c.u = ((unsigned int)u) << 16;
    return c.f;
}
__device__ __forceinline__ float gelu_fast(float x) {
    float x2 = x * x;
    float y2 = 1.5957691216057308f * (x + 0.044715f * x2 * x);
    float e = __expf(y2);
    float t = 1.0f - 2.0f * __builtin_amdgcn_rcpf(e + 1.0f);
    return 0.5f * x * (1.0f + t);
}

typedef const __attribute__((address_space(1))) void* gas_t;
typedef __attribute__((address_space(3))) void* las_t;
__device__ __forceinline__ void g2l16(const void* g, void* l) {
    __builtin_amdgcn_global_load_lds((gas_t)g, (las_t)l, 16, 0, 0);
}

// pack 4 floats -> 4 fp8 e4m3 bytes (RNE, saturating)
__device__ __forceinline__ unsigned int f4_to_fp8x4(float a, float b, float c, float d) {
    int lo = __builtin_amdgcn_cvt_pk_fp8_f32(a, b, 0, 0);
    return (unsigned int)__builtin_amdgcn_cvt_pk_fp8_f32(c, d, lo, 1);
}
__device__ __forceinline__ unsigned char f_to_fp8(float a) {
    return (unsigned char)(__builtin_amdgcn_cvt_pk_fp8_f32(a, a, 0, 0) & 0xFF);
}

// ---------------- fused prep kernel ----------------
#define PREP_Q    96
#define PREP_TR1E 240
#define PREP_TR2E 312
#define PREP_END  12600

__global__ __launch_bounds__(256) void prep_kernel(
    const float* __restrict__ segments, unsigned char* __restrict__ segF8,
    const float* __restrict__ W1, unsigned char* __restrict__ W1t8,
    const float* __restrict__ W2, unsigned char* __restrict__ W2t8,
    const float* __restrict__ questions, float* __restrict__ qW1p,
    const int* __restrict__ nseg)
{
    __shared__ __align__(16) char sh[34816];   // max(q-branch 2x64x68 f32, transpose 64x65 f32)
    const int bid = blockIdx.x, tid = threadIdx.x;

    if (bid < PREP_Q) {
        // q-GEMM: questions[128,768] @ W1[:768] -> qW1p[4][128][768]
        // 96 blocks = 4 ksplits x 2 m-tiles(64) x 12 n-tiles(64).
        // 64-wide K chunks, one barrier pair per chunk (3 chunks).
        float (*As)[68] = (float(*)[68])sh;               // [k][m] transposed
        float (*Bs)[68] = (float(*)[68])(sh + 17408);     // [k][n]
        const int s = bid / 24, rem = bid % 24;
        const int n0 = (rem % 12) * 64, m0 = (rem / 12) * 64;
        const int tn = tid & 15, tm = tid >> 4;
        const int lr = tid >> 2;            // 0..63: A-row / B-k-row
        const int lc = tid & 3;             // column-chunk selector
        float acc[4][4] = {};
        const int kbeg = s * 192;
        for (int kc = kbeg; kc < kbeg + 192; kc += 64) {
            // stage A transposed: thread covers float4s at kk = lc*4 + 16p
            const float* ap = questions + (size_t)(m0 + lr) * 768 + kc;
            #pragma unroll
            for (int p = 0; p < 4; p++) {
                int kk = lc * 4 + 16 * p;
                float4 v = *(const float4*)(ap + kk);
                As[kk + 0][lr] = v.x; As[kk + 1][lr] = v.y;
                As[kk + 2][lr] = v.z; As[kk + 3][lr] = v.w;
            }
            // stage B row-major: W1[kc+lr][n0 + lc*16 + 4p ..]
            const float* bp = W1 + (size_t)(kc + lr) * 768 + n0 + lc * 16;
            #pragma unroll
            for (int p = 0; p < 4; p++)
                *(float4*)&Bs[lr][lc * 16 + 4 * p] = *(const float4*)(bp + 4 * p);
            __syncthreads();
            #pragma unroll 2
            for (int k = 0; k < 64; k++) {
                float4 a = *(const float4*)&As[k][tm * 4];
                float4 b = *(const float4*)&Bs[k][tn * 4];
                float ar4[4] = {a.x, a.y, a.z, a.w};
                float br4[4] = {b.x, b.y, b.z, b.w};
                #pragma unroll
                for (int i = 0; i < 4; i++)
                    #pragma unroll
                    for (int j = 0; j < 4; j++)
                        acc[i][j] += ar4[i] * br4[j];
            }
            __syncthreads();
        }
        float* outp = qW1p + (size_t)s * 128 * 768;
        #pragma unroll
        for (int i = 0; i < 4; i++) {
            int row = m0 + tm * 4 + i;
            *(float4*)&outp[(size_t)row * 768 + n0 + tn * 4] =
                make_float4(acc[i][0], acc[i][1], acc[i][2], acc[i][3]);
        }
        return;
    }

    if (bid < PREP_TR2E) {
        // transpose 64x64 tile -> fp8 bytes
        const float* in; unsigned char* outp; int R, C, bx, by;
        if (bid < PREP_TR1E) {
            int idx = bid - PREP_Q; bx = idx % 12; by = idx / 12;
            in = W1 + 768 * 768; outp = W1t8; R = 768; C = 768;
        } else {
            int idx = bid - PREP_TR1E; bx = idx % 6; by = idx / 6;
            in = W2; outp = W2t8; R = 768; C = 384;
        }
        float (*t)[65] = (float(*)[65])sh;
        int r0 = by * 64, c0 = bx * 64;
        int tx = tid & 63, ty = tid >> 6;
        #pragma unroll
        for (int p = 0; p < 16; p++) {
            int row = ty * 16 + p;
            t[row][tx] = in[(size_t)(r0 + row) * C + c0 + tx];
        }
        __syncthreads();
        #pragma unroll
        for (int p = 0; p < 16; p++) {
            int orow = ty * 16 + p;
            outp[(size_t)(c0 + orow) * R + r0 + tx] = f_to_fp8(t[tx][orow]);
        }
        return;
    }

    // conv: segments fp32 -> segF8 fp8 (8 elems/thread, 2048 elems/block).
    // 196608 elems/bag is a multiple of 2048 -> each block is within ONE bag.
    // Skip blocks whose rows are all masked (row_in_bag >= nseg[bag]).
    {
        int cb = bid - PREP_TR2E;
        int row0 = (cb * 2048) / 768;           // first segment-row this block touches
        if ((row0 & 255) >= nseg[row0 >> 8]) return;
        long i = (long)cb * 256 + tid;
        const float4* in = (const float4*)segments;
        float4 a = in[2 * i], b = in[2 * i + 1];
        unsigned int lo = f4_to_fp8x4(a.x, a.y, a.z, a.w);
        unsigned int hi = f4_to_fp8x4(b.x, b.y, b.z, b.w);
        *(uint2*)(segF8 + i * 8) = make_uint2(lo, hi);
    }
}

// ---------------- fp8 MX-scaled MFMA GEMM ----------------
// C[M,N] = gelu(A8[M,K] @ Bt8[N,K]^T + bias + optional sum qW1p[bag])
// MODE 1: output fp8 bytes to global (K2)
// MODE 2: fuse W3 GEMV: output partial preds fp32 [gridDim.x][M][4] (K3)
// 128x128 block, 4 waves, wave 64x64 = 2x2 of 32x32x64 f8f6f4 (unit scales).
// Each m-block covers one 128-row bag-half; exits if those rows are all masked.
template<int MODE>
__global__ __launch_bounds__(256) void mfma_gemm_f8(
    const unsigned char* __restrict__ A8,    // [M,K] fp8
    const unsigned char* __restrict__ Bt8,   // [N,K] fp8
    const float* __restrict__ bias,          // [N]
    const float* __restrict__ rowAdd,        // [4][128,N] partials or null
    void* __restrict__ CoutV,                // [M,N] fp8, or [gx][M][4] f32
    int M, int N, int K,
    const float* __restrict__ W3p,           // [N][4] (MODE 2 only)
    const int* __restrict__ nseg)
{
    __shared__ __align__(16) unsigned char smem8[32768 + (MODE == 2 ? 2048 : 0)];
    unsigned char* As = smem8;             // [128][64B] swizzled (8KB)
    unsigned char* Bs = smem8 + 8192;      // [128][64B] (8KB)
    const int tid = threadIdx.x;
    const int wave = tid >> 6, lane = tid & 63;
    const int m0 = blockIdx.y * 128, n0 = blockIdx.x * 128;

    // dead bag-half elision: rows [m0&255, (m0&255)+128) of bag m0>>8
    if (nseg[m0 >> 8] <= (m0 & 255)) return;

    const int wm = (wave & 1) * 64, wn = (wave >> 1) * 64;

    if constexpr (MODE == 2) {
        // stash W3 chunk for this n-tile (cols n0..n0+127) beyond the tile buffer
        if (tid < 128)
            ((float4*)(smem8 + 32768))[tid] = ((const float4*)W3p)[n0 + tid];
    }

    f32x16 acc[2][2] = {};

    const int srow = tid >> 2;
    const int schunk = (tid & 3) ^ ((srow >> 1) & 3);
    const unsigned char* Ag = A8 + (size_t)(m0 + srow) * K + schunk * 16;
    const unsigned char* Bg = Bt8 + (size_t)(n0 + srow) * K + schunk * 16;
    unsigned char* Al = As + tid * 16;
    unsigned char* Bl = Bs + tid * 16;

    const int fm = lane & 31, fq = lane >> 5;

    for (int k0 = 0; k0 < K; k0 += 64) {
        g2l16(Ag + k0, Al);
        g2l16(Ag + (size_t)64 * K + k0, Al + 4096);
        g2l16(Bg + k0, Bl);
        g2l16(Bg + (size_t)64 * K + k0, Bl + 4096);
        __syncthreads();

        i32x8 av[2], bv[2];
        #pragma unroll
        for (int i = 0; i < 2; i++) {
            int rw = wm + i * 32 + fm, key = (rw >> 1) & 3;
            i32x4 lo = *(const i32x4*)&As[rw * 64 + (((fq << 1) | 0) ^ key) * 16];
            i32x4 hi = *(const i32x4*)&As[rw * 64 + (((fq << 1) | 1) ^ key) * 16];
            av[i][0] = lo[0]; av[i][1] = lo[1]; av[i][2] = lo[2]; av[i][3] = lo[3];
            av[i][4] = hi[0]; av[i][5] = hi[1]; av[i][6] = hi[2]; av[i][7] = hi[3];
        }
        #pragma unroll
        for (int j = 0; j < 2; j++) {
            int rw = wn + j * 32 + fm, key = (rw >> 1) & 3;
            i32x4 lo = *(const i32x4*)&Bs[rw * 64 + (((fq << 1) | 0) ^ key) * 16];
            i32x4 hi = *(const i32x4*)&Bs[rw * 64 + (((fq << 1) | 1) ^ key) * 16];
            bv[j][0] = lo[0]; bv[j][1] = lo[1]; bv[j][2] = lo[2]; bv[j][3] = lo[3];
            bv[j][4] = hi[0]; bv[j][5] = hi[1]; bv[j][6] = hi[2]; bv[j][7] = hi[3];
        }
        #pragma unroll
        for (int i = 0; i < 2; i++)
            #pragma unroll
            for (int j = 0; j < 2; j++)
                acc[i][j] = __builtin_amdgcn_mfma_scale_f32_32x32x64_f8f6f4(
                    av[i], bv[j], acc[i][j], 0, 0,   // cbsz=fp8, blgp=fp8
                    0, 127, 0, 127);                 // unit e8m0 scales
        __syncthreads();
    }

    // Epilogue (C/D: col=lane&31, row=(reg&3)+8*(reg>>2)+4*(lane>>5)), gelu
    #pragma unroll
    for (int j = 0; j < 2; j++) {
        int coll = wn + j * 32 + fm;
        int col = n0 + coll;
        float add = bias[col];
        if (rowAdd) {
            const float* radd = rowAdd + (size_t)(m0 >> 8) * N;
            add += radd[col] + radd[col + 98304] +
                   radd[col + 2 * 98304] + radd[col + 3 * 98304];
        }
        #pragma unroll
        for (int i = 0; i < 2; i++) {
            int rbase = wm + i * 32 + 4 * fq;
            #pragma unroll
            for (int reg = 0; reg < 16; reg++) {
                int rowl = rbase + (reg & 3) + 8 * (reg >> 2);
                float v = gelu_fast(acc[i][j][reg] + add);
                if constexpr (MODE == 1) smem8[rowl * 128 + coll] = f_to_fp8(v);
                else ((unsigned short*)smem8)[rowl * 128 + coll] = f2bf(v);
            }
        }
    }
    __syncthreads();
    if constexpr (MODE == 1) {
        unsigned char* Cout = (unsigned char*)CoutV;
        #pragma unroll
        for (int it = 0; it < 4; it++) {
            int idx = it * 256 + tid;
            int r = idx >> 3, cc = (idx & 7) * 16;
            *(uint4*)&Cout[(size_t)(m0 + r) * N + n0 + cc] =
                *(const uint4*)&smem8[r * 128 + cc];
        }
    } else if constexpr (MODE == 2) {
        // per-row GEMV with the W3 chunk: 2 threads/row, 64 cols each.
        // XOR the chunk order with (r&7) to spread the 256B-stride rows
        // across banks (avoids a 32-way conflict on b128 LDS reads).
        const float4* w3sh = (const float4*)(smem8 + 32768);
        const unsigned short* tile = (const unsigned short*)smem8;
        int r = tid >> 1, ch = tid & 1;
        const unsigned short* rowp = tile + r * 128 + ch * 64;
        float4 a = make_float4(0.f, 0.f, 0.f, 0.f);
        #pragma unroll
        for (int k = 0; k < 8; k++) {
            int kk = k ^ (r & 7);
            ushort8 u = *(const ushort8*)(rowp + kk * 8);
            #pragma unroll
            for (int jj = 0; jj < 8; jj++) {
                float h = bf2f(u[jj]);
                float4 wv2 = w3sh[ch * 64 + kk * 8 + jj];
                a.x += h * wv2.x; a.y += h * wv2.y;
                a.z += h * wv2.z; a.w += h * wv2.w;
            }
        }
        // combine the two column-halves (lanes 2r, 2r+1 are wave-adjacent)
        a.x += __shfl_xor(a.x, 1); a.y += __shfl_xor(a.y, 1);
        a.z += __shfl_xor(a.z, 1); a.w += __shfl_xor(a.w, 1);
        if (ch == 0)
            ((float4*)CoutV)[(size_t)blockIdx.x * 32768 + m0 + r] = a;
    }
}

// ---------------- head: softmax + aggregation over partial preds ----------------
__device__ __forceinline__ float4 f4mul(float4 a, float4 b) {
    return make_float4(a.x * b.x, a.y * b.y, a.z * b.z, a.w * b.w);
}

// block-wide inclusive product-scan of 256 float4 via wave shfl scans.
__device__ __forceinline__ float4 block_scan_prod(float4 v, int lane, int wv,
                                                  float4* wtot) {
    #pragma unroll
    for (int off = 1; off < 64; off <<= 1) {
        float4 t;
        t.x = __shfl_up(v.x, off); t.y = __shfl_up(v.y, off);
        t.z = __shfl_up(v.z, off); t.w = __shfl_up(v.w, off);
        if (lane >= off) v = f4mul(v, t);
    }
    if (lane == 63) wtot[wv] = v;
    __syncthreads();
    float4 pre = make_float4(1.f, 1.f, 1.f, 1.f);
    #pragma unroll
    for (int w = 0; w < 3; w++)
        if (w < wv) pre = f4mul(pre, wtot[w]);
    __syncthreads();
    return f4mul(pre, v);
}

__global__ __launch_bounds__(256) void head_kernel(
    const float* __restrict__ pp,   // [3][32768][4] partial preds
    const float* __restrict__ b3,
    const int* __restrict__ nseg,
    float* __restrict__ out)
{
    __shared__ float4 xbuf[256];
    __shared__ float4 wtot[4];
    const int b = blockIdx.x, tid = threadIdx.x;
    const int lane = tid & 63, wv = tid >> 6;
    const float4 ones = make_float4(1.f, 1.f, 1.f, 1.f);

    const float4* ppv = (const float4*)pp;
    size_t row = (size_t)b * 256 + tid;
    float4 a0 = ppv[row], a1 = ppv[row + 32768], a2 = ppv[row + 65536];
    float4 acc = make_float4(a0.x + a1.x + a2.x + b3[0],
                             a0.y + a1.y + a2.y + b3[1],
                             a0.z + a1.z + a2.z + b3[2],
                             a0.w + a1.w + a2.w + b3[3]);
    float m = fmaxf(fmaxf(acc.x, acc.y), fmaxf(acc.z, acc.w));
    float e0 = __expf(acc.x - m), e1 = __expf(acc.y - m),
          e2 = __expf(acc.z - m), e3 = __expf(acc.w - m);
    float inv = 1.0f / (e0 + e1 + e2 + e3);
    float4 p = make_float4(e0 * inv, e1 * inv, e2 * inv, e3 * inv);

    const int n = nseg[b];
    bool msk = tid < n;
    float s1 = p.x, s2 = s1 + p.y, s3 = s2 + p.z;
    float4 sm = msk ? make_float4(0.f, s1, s2, s3) : ones;

    // inclusive prefix scan -> exclusive prefix pfx
    float4 isc = block_scan_prod(sm, lane, wv, wtot);
    xbuf[tid] = isc;
    __syncthreads();
    float4 pfx = (tid > 0) ? xbuf[tid - 1] : ones;
    __syncthreads();

    // reversed scan -> exclusive suffix sfx
    xbuf[255 - tid] = sm;
    __syncthreads();
    float4 rsm = xbuf[tid];
    __syncthreads();
    float4 risc = block_scan_prod(rsm, lane, wv, wtot);
    xbuf[tid] = risc;
    __syncthreads();
    float4 sfx = (tid < 255) ? xbuf[254 - tid] : ones;
    __syncthreads();

    float4 L = f4mul(pfx, sfx);        // leave-one-out products
    float4 cpL = block_scan_prod(L, lane, wv, wtot);

    float4 term = msk ? f4mul(p, cpL) : make_float4(0.f, 0.f, 0.f, 0.f);
    float4 pm = msk ? p : ones;
    #pragma unroll
    for (int off = 32; off > 0; off >>= 1) {
        term.x += __shfl_xor(term.x, off); term.y += __shfl_xor(term.y, off);
        term.z += __shfl_xor(term.z, off); term.w += __shfl_xor(term.w, off);
        pm.x *= __shfl_xor(pm.x, off); pm.y *= __shfl_xor(pm.y, off);
        pm.z *= __shfl_xor(pm.z, off); pm.w *= __shfl_xor(pm.w, off);
    }
    if (lane == 0) { xbuf[wv] = term; xbuf[4 + wv] = pm; }
    __syncthreads();
    if (tid == 0) {
        float4 st = make_float4(0.f, 0.f, 0.f, 0.f);
        float4 pr = ones;
        #pragma unroll
        for (int w = 0; w < 4; w++) {
            float4 t = xbuf[w], q = xbuf[4 + w];
            st.x += t.x; st.y += t.y; st.z += t.z; st.w += t.w;
            pr = f4mul(pr, q);
        }
        ((float4*)out)[b] = make_float4(0.25f * st.x + pr.x,
                                        0.25f * st.y + pr.y,
                                        0.25f * st.z + pr.z,
                                        0.25f * st.w + pr.w);
    }
}

extern "C" void kernel_launch(void* const* d_in, const int* in_sizes, int n_in,
                              void* d_out, int out_size, void* d_ws, size_t ws_size,
                              hipStream_t stream) {
    (void)in_sizes; (void)n_in; (void)out_size; (void)ws_size;
    const float* questions = (const float*)d_in[0];
    const float* segments  = (const float*)d_in[1];
    const float* W1 = (const float*)d_in[2];
    const float* b1 = (const float*)d_in[3];
    const float* W2 = (const float*)d_in[4];
    const float* b2 = (const float*)d_in[5];
    const float* W3 = (const float*)d_in[6];
    const float* b3 = (const float*)d_in[7];
    const int*  nseg = (const int*)d_in[8];
    float* out = (float*)d_out;

    char* w = (char*)d_ws;
    float* qW1p = (float*)w;                   w += (size_t)4 * 128 * 768 * 4;
    unsigned char*  W1t8 = (unsigned char*)w;  w += (size_t)768 * 768;
    unsigned char*  W2t8 = (unsigned char*)w;  w += (size_t)384 * 768;
    unsigned char*  segF8 = (unsigned char*)w; w += (size_t)32768 * 768;
    unsigned char*  H1f8 = (unsigned char*)w;  w += (size_t)32768 * 768;
    float* ppreds = (float*)w;                 w += (size_t)3 * 32768 * 4 * 4;

    prep_kernel<<<PREP_END, 256, 0, stream>>>(
        segments, segF8, W1, W1t8, W2, W2t8, questions, qW1p, nseg);
    // K2 (fp8 -> fp8): grid (n=6, m=256)
    mfma_gemm_f8<1><<<dim3(6, 256), 256, 0, stream>>>(
        segF8, W1t8, b1, qW1p, H1f8, 32768, 768, 768, nullptr, nseg);
    // K3 (fp8 -> fused W3 partial preds): grid (n=3, m=256)
    mfma_gemm_f8<2><<<dim3(3, 256), 256, 0, stream>>>(
        H1f8, W2t8, b2, nullptr, ppreds, 32768, 384, 768, W3, nseg);
    head_kernel<<<128, 256, 0, stream>>>(ppreds, b3, nseg, out);
}